// Round 5
// baseline (397.973 us; speedup 1.0000x reference)
//
#include <hip/hip_runtime.h>
#include <hip/hip_bf16.h>

// Problem constants
#define C      128
#define SP     21952          // 28*28*28
#define PT     87808          // 4*SP
#define LW     343            // 7^3 window length
#define EPS_   1e-6f
#define SCALE_ 0.17677669529663687f  // 32^-0.5

// misc workspace layout (floats)
#define MISC_A   0
#define MISC_B   128
#define MISC_BQK 256
#define MISC_BV  512
#define MISC_SUM 640
#define MISC_SQ  768
#define MISC_A2  896
#define MISC_B2  1024
#define MISC_XS  1152
#define MISC_XQ  1280

typedef __attribute__((ext_vector_type(8))) short bf16x8;
typedef __attribute__((ext_vector_type(4))) float f32x4;

__device__ __forceinline__ float b2f(unsigned short u){
  return __uint_as_float(((unsigned int)u) << 16);
}
__device__ __forceinline__ unsigned short f2b(float f){
  unsigned int u = __float_as_uint(f);
  u += 0x7fffu + ((u >> 16) & 1u);     // round-to-nearest-even
  return (unsigned short)(u >> 16);
}

// K0: per-channel partial sum/sumsq of x, 1024 blocks, float4 loads.
__global__ __launch_bounds__(256) void k0_partial(const float* __restrict__ x,
                                                  float* __restrict__ misc){
  int c = blockIdx.x & 127, chunk = blockIdx.x >> 7;   // 8 chunks = 4 batch x 2 halves
  int bb = chunk >> 1, half = chunk & 1;
  const float4* p = reinterpret_cast<const float4*>(
      x + (size_t)(bb*C + c)*SP + half*10976);
  int t = threadIdx.x;
  float s = 0.f, ss = 0.f;
  for (int i = t; i < 2744; i += 256){
    float4 v = p[i];
    s  += v.x + v.y + v.z + v.w;
    ss += v.x*v.x + v.y*v.y + v.z*v.z + v.w*v.w;
  }
  #pragma unroll
  for (int off = 32; off > 0; off >>= 1){
    s  += __shfl_xor(s,  off);
    ss += __shfl_xor(ss, off);
  }
  __shared__ float red[8];
  int wid = t >> 6, lane = t & 63;
  if (lane == 0){ red[wid] = s; red[4+wid] = ss; }
  __syncthreads();
  if (t == 0){
    atomicAdd(&misc[MISC_XS + c], red[0]+red[1]+red[2]+red[3]);
    atomicAdd(&misc[MISC_XQ + c], red[4]+red[5]+red[6]+red[7]);
  }
}

// K1: finalize BN stats (from k0 partials) + fold shift through 1x1 weights.
__global__ void k1_bias(const float* __restrict__ wqk, const float* __restrict__ wvv,
                        const float* __restrict__ gin, const float* __restrict__ bin,
                        float* __restrict__ misc){
  __shared__ float bv[128];
  int t = threadIdx.x;          // 128 threads, grid 3
  {
    float mean = misc[MISC_XS + t] / (float)PT;
    float var  = misc[MISC_XQ + t] / (float)PT - mean*mean;
    float a = rsqrtf(var + EPS_) * gin[t];
    float bb = bin[t] - mean * a;
    bv[t] = bb;
    if (blockIdx.x == 0){ misc[MISC_A + t] = a; misc[MISC_B + t] = bb; }
  }
  __syncthreads();
  int o = blockIdx.x*128 + t;
  float acc = 0.f;
  if (o < 256){
    const float* wr = wqk + (size_t)o*128;
    for (int c = 0; c < 128; ++c) acc += wr[c]*bv[c];
    misc[MISC_BQK + o] = acc;
  } else {
    const float* wr = wvv + (size_t)(o-256)*128;
    for (int c = 0; c < 128; ++c) acc += wr[c]*bv[c];
    misc[MISC_BV + (o-256)] = acc;
  }
}

// K1w: split qkv weights into bf16 hi/lo pairs: w2[0..49152) = hi, [49152..) = lo
__global__ void k1w(const float* __restrict__ wqk, const float* __restrict__ wvv,
                    unsigned short* __restrict__ w2){
  int idx = blockIdx.x*256 + threadIdx.x;   // 49152 total
  int o = idx >> 7;
  float w = (o < 256) ? wqk[idx] : wvv[idx - 32768];
  unsigned short h = f2b(w);
  w2[idx] = h;
  w2[49152 + idx] = f2b(w - b2f(h));
}

// K2 (MFMA): qkv projection on mfma_f32_16x16x32_bf16 with split-bf16
// fp32 emulation: out = xh*wh + xl*wh + xh*wl (missing xl*wl ~ 2^-18 relative).
__global__ __launch_bounds__(256) void k2_qkv(const float* __restrict__ x,
        const unsigned short* __restrict__ w2, const float* __restrict__ misc,
        unsigned short* __restrict__ qg, unsigned short* __restrict__ kg,
        unsigned short* __restrict__ vg){
  __shared__ __align__(16) unsigned short xh[8192];   // 16KB
  __shared__ __align__(16) unsigned short xl[8192];   // 16KB
  __shared__ float ascale[128];
  __shared__ unsigned int posTab[64];
  int t = threadIdx.x;
  int P0 = blockIdx.x * 64;
  int b = P0 / SP, sp0 = P0 % SP;
  if (t < 128) ascale[t] = misc[MISC_A + t];
  if (t < 64){
    int sp = sp0 + t;
    int h_ = sp / 784, rem = sp % 784;
    int w_ = rem / 28, d_ = rem % 28;
    int w1 = h_ & 3, s1 = h_ >> 2;
    int w2i = w_ & 3, s2 = w_ >> 2;
    int w3 = d_ & 3, s3 = d_ >> 2;
    int bw = ((b*4 + w1)*4 + w2i)*4 + w3;
    int l  = (s1*7 + s2)*7 + s3;
    posTab[t] = (unsigned int)(bw*43904 + l*32);   // ushort offset, +h*10976+d at store
  }
  __syncthreads();
  // stage x -> bf16 hi/lo (BN scale folded), swizzled
  {
    int p = t & 63;
    int ob = t >> 6;
    const float* xb = x + (size_t)b*C*SP + sp0 + p;
    for (int it = 0; it < 4; ++it){
      int c0 = (ob + it*4) * 8;
      unsigned int ph[4], pl[4];
      #pragma unroll
      for (int j = 0; j < 4; ++j){
        float f0 = xb[(size_t)(c0 + 2*j)*SP]     * ascale[c0 + 2*j];
        float f1 = xb[(size_t)(c0 + 2*j + 1)*SP] * ascale[c0 + 2*j + 1];
        unsigned short h0 = f2b(f0), h1 = f2b(f1);
        unsigned short l0 = f2b(f0 - b2f(h0)), l1 = f2b(f1 - b2f(h1));
        ph[j] = (unsigned int)h0 | ((unsigned int)h1 << 16);
        pl[j] = (unsigned int)l0 | ((unsigned int)l1 << 16);
      }
      int byte = (p*256 + c0*2) ^ ((p & 7) << 4);
      *reinterpret_cast<uint4*>((char*)xh + byte) = make_uint4(ph[0],ph[1],ph[2],ph[3]);
      *reinterpret_cast<uint4*>((char*)xl + byte) = make_uint4(pl[0],pl[1],pl[2],pl[3]);
    }
  }
  __syncthreads();
  int wid = t >> 6, lane = t & 63;
  int g = lane >> 4, ln = lane & 15;
  int wstart = wid * 96;
  f32x4 acc[6][4];
  #pragma unroll
  for (int nt = 0; nt < 6; ++nt){
    float bv = misc[256 + wstart + nt*16 + ln];
    #pragma unroll
    for (int mt = 0; mt < 4; ++mt) acc[nt][mt] = (f32x4){bv,bv,bv,bv};
  }
  #pragma unroll 1
  for (int kk = 0; kk < 4; ++kk){
    bf16x8 ah[4], al[4];
    #pragma unroll
    for (int mt = 0; mt < 4; ++mt){
      int row = mt*16 + ln;
      int byte = (row*256 + kk*64 + g*16) ^ ((ln & 7) << 4);
      ah[mt] = *reinterpret_cast<const bf16x8*>((const char*)xh + byte);
      al[mt] = *reinterpret_cast<const bf16x8*>((const char*)xl + byte);
    }
    #pragma unroll
    for (int nt = 0; nt < 6; ++nt){
      int o = wstart + nt*16 + ln;
      const unsigned short* wp = w2 + (size_t)o*128 + kk*32 + g*8;
      bf16x8 whf = *reinterpret_cast<const bf16x8*>(wp);
      bf16x8 wlf = *reinterpret_cast<const bf16x8*>(wp + 49152);
      #pragma unroll
      for (int mt = 0; mt < 4; ++mt){
        acc[nt][mt] = __builtin_amdgcn_mfma_f32_16x16x32_bf16(ah[mt], whf, acc[nt][mt], 0, 0, 0);
        acc[nt][mt] = __builtin_amdgcn_mfma_f32_16x16x32_bf16(al[mt], whf, acc[nt][mt], 0, 0, 0);
        acc[nt][mt] = __builtin_amdgcn_mfma_f32_16x16x32_bf16(ah[mt], wlf, acc[nt][mt], 0, 0, 0);
      }
    }
  }
  // epilogue: relu on v, bf16, scatter (16 consecutive lanes = 32B contiguous)
  unsigned int ptab[16];
  #pragma unroll
  for (int mt = 0; mt < 4; ++mt)
    #pragma unroll
    for (int r = 0; r < 4; ++r)
      ptab[mt*4+r] = posTab[mt*16 + g*4 + r];
  #pragma unroll
  for (int nt = 0; nt < 6; ++nt){
    int o = wstart + nt*16 + ln;
    bool isv = (o >= 256);
    int oo = o & 127;
    unsigned short* dst = ((o < 128) ? qg : (o < 256 ? kg : vg)) + (oo >> 5)*10976 + (oo & 31);
    #pragma unroll
    for (int mt = 0; mt < 4; ++mt){
      #pragma unroll
      for (int r = 0; r < 4; ++r){
        float v = acc[nt][mt][r];
        if (isv) v = fmaxf(v, 0.f);
        dst[ptab[mt*4+r]] = f2b(v);
      }
    }
  }
}

// K3 (MFMA): attention per (window, head) on mfma_f32_16x16x32_bf16.
__global__ __launch_bounds__(256) void k3_attn(const unsigned short* __restrict__ qg,
        const unsigned short* __restrict__ kg, const unsigned short* __restrict__ vg,
        unsigned short* __restrict__ xatt){
  __shared__ __align__(16) unsigned short klds[352*32];    // [m][d]     22528 B
  __shared__ __align__(16) unsigned short vper[32*360];    // [d][m']    23040 B
  __shared__ __align__(16) unsigned short pbuf[4][640];    // per-wave [16][40]
  int bh = blockIdx.x;
  int bw = bh >> 2, h = bh & 3;
  int t = threadIdx.x;
  int wid = t >> 6, lane = t & 63;
  int g = lane >> 4, ln = lane & 15;
  const unsigned short* kbase = kg + (size_t)bh*LW*32;
  const unsigned short* vbase = vg + (size_t)bh*LW*32;
  const unsigned short* qbase = qg + (size_t)bh*LW*32;
  // stage K: straight uint4 copy, zero pad rows 343..351
  {
    const uint4* src = reinterpret_cast<const uint4*>(kbase);
    uint4* dst = reinterpret_cast<uint4*>(klds);
    for (int i = t; i < 1372; i += 256) dst[i] = src[i];
    for (int i = t; i < 288; i += 256) klds[10976 + i] = 0;
  }
  // stage V transposed + 32-key interleave: m -> (c = m>>5, pk = 2*(m&15) | ((m>>4)&1))
  for (int idx = t; idx < 10976; idx += 256){
    int m = idx >> 5, d = idx & 31;
    int km = m & 31;
    int pk = ((km & 15) << 1) | (km >> 4);
    vper[d*360 + ((m >> 5) << 5) + pk] = vbase[idx];
  }
  for (int i = t; i < 288; i += 256){       // zero V pad rows 343..351
    int m = 343 + (i >> 5), d = i & 31;
    int km = m & 31;
    int pk = ((km & 15) << 1) | (km >> 4);
    vper[d*360 + 320 + pk] = 0;
  }
  __syncthreads();
  int w1 = (bw>>4)&3, w2 = (bw>>2)&3, w3 = bw&3, b = bw>>6;
  unsigned short* pb = pbuf[wid];
  const f32x4 zero4 = {0.f, 0.f, 0.f, 0.f};
  for (int rt = wid; rt < 22; rt += 4){
    int row0 = rt << 4;
    bf16x8 qf = *reinterpret_cast<const bf16x8*>(qbase + (size_t)(row0 + ln)*32 + g*8);
    // QK^T: 22 n-tiles, single k-step (K=32=DH)
    f32x4 s[22];
    #pragma unroll
    for (int nt = 0; nt < 22; ++nt){
      bf16x8 kf = *reinterpret_cast<const bf16x8*>(&klds[(nt*16 + ln)*32 + g*8]);
      s[nt] = __builtin_amdgcn_mfma_f32_16x16x32_bf16(qf, kf, zero4, 0, 0, 0);
    }
    float mxs[4];
    #pragma unroll
    for (int q = 0; q < 4; ++q){
      float m0 = -1e30f;
      #pragma unroll
      for (int nt = 0; nt < 21; ++nt) m0 = fmaxf(m0, s[nt][q]);
      if (ln < 7) m0 = fmaxf(m0, s[21][q]);
      #pragma unroll
      for (int off = 8; off > 0; off >>= 1) m0 = fmaxf(m0, __shfl_xor(m0, off));
      mxs[q] = m0 * SCALE_;
    }
    f32x4 o0 = zero4, o1 = zero4;
    float sums[4] = {0.f, 0.f, 0.f, 0.f};
    #pragma unroll
    for (int c = 0; c < 11; ++c){
      #pragma unroll
      for (int q = 0; q < 4; ++q){
        float e0 = __expf(fmaf(s[2*c][q],   SCALE_, -mxs[q]));
        float e1 = (c*32 + 16 + ln < 343)
                 ? __expf(fmaf(s[2*c+1][q], SCALE_, -mxs[q])) : 0.f;
        sums[q] += e0 + e1;
        unsigned int pkd;
        asm volatile("v_cvt_pk_bf16_f32 %0, %1, %2" : "=v"(pkd) : "v"(e0), "v"(e1));
        *reinterpret_cast<unsigned int*>(&pb[(g*4+q)*40 + (ln<<1)]) = pkd;
      }
      asm volatile("s_waitcnt lgkmcnt(0)" ::: "memory");
      __builtin_amdgcn_sched_barrier(0);
      bf16x8 pa  = *reinterpret_cast<const bf16x8*>(&pb[ln*40 + g*8]);
      bf16x8 vb0 = *reinterpret_cast<const bf16x8*>(&vper[ln*360       + (c<<5) + g*8]);
      bf16x8 vb1 = *reinterpret_cast<const bf16x8*>(&vper[(16+ln)*360  + (c<<5) + g*8]);
      o0 = __builtin_amdgcn_mfma_f32_16x16x32_bf16(pa, vb0, o0, 0, 0, 0);
      o1 = __builtin_amdgcn_mfma_f32_16x16x32_bf16(pa, vb1, o1, 0, 0, 0);
    }
    float iss[4];
    #pragma unroll
    for (int q = 0; q < 4; ++q){
      float sq = sums[q];
      #pragma unroll
      for (int off = 8; off > 0; off >>= 1) sq += __shfl_xor(sq, off);
      iss[q] = 1.f / sq;
    }
    #pragma unroll
    for (int q = 0; q < 4; ++q){
      int l = row0 + g*4 + q;
      if (l < 343){
        int ss1 = l/49, ss2 = (l/7)%7, ss3 = l%7;
        int sp = (ss1*4+w1)*784 + (ss2*4+w2)*28 + (ss3*4+w3);
        size_t gaddr = ((size_t)b*SP + sp)*128 + h*32;
        xatt[gaddr + ln]      = f2b(o0[q]*iss[q]);
        xatt[gaddr + 16 + ln] = f2b(o1[q]*iss[q]);
      }
    }
  }
}

// K_wprep: w_cl [oc][ic][27] fp32 -> wbf bf16 slices [h][tap][kg][oc][8]
__global__ void k_wprep(const float* __restrict__ wcl, unsigned short* __restrict__ wbf){
  int f = blockIdx.x*256 + threadIdx.x;      // 442368 total
  int j  = f & 7;
  int oc = (f >> 3) & 127;
  int kgr= (f >> 10) & 7;
  int sl = f >> 13;                          // 0..53
  int h  = sl / 27, tap = sl % 27;
  int ic = h*64 + kgr*8 + j;
  wbf[f] = f2b(wcl[((size_t)oc*128 + ic)*27 + tap]);
}

// K6w: split proj weights into bf16 hi/lo pairs: w6[0..16384) hi, [16384..) lo
__global__ void k6w(const float* __restrict__ wproj, unsigned short* __restrict__ w6){
  int idx = blockIdx.x*256 + threadIdx.x;   // 16384 total
  float w = wproj[idx];
  unsigned short h = f2b(w);
  w6[idx] = h;
  w6[16384 + idx] = f2b(w - b2f(h));
}

// K4 v3: 3x3x3 conv as implicit GEMM on mfma_f32_16x16x32_bf16.
// v2 post-mortem: VGPR_Count=88 proved the compiler sank the B prefetch
// (b0/b1 can't fit) -> per-tap L2 latency exposed serially, MfmaUtil 28%.
// v3: (1) __launch_bounds__(256,2) concedes 2 waves/SIMD so the allocator
// can hold the double buffer; (2) dual spatial tile per block (2x64 pos,
// 4 waves = {tile}x{oc-half}) -> 686 blocks, whole grid ~co-resident at
// 2 blocks/CU, 2 independent waves/SIMD cross-cover L2+LDS latency;
// (3) halo[2][...] 55.3KB, still only 2 barriers per h-half, no per-tap sync.
__global__ __launch_bounds__(256, 2) void k4_mfma(const unsigned short* __restrict__ xag,
        const unsigned short* __restrict__ wbf, unsigned short* __restrict__ yg){
  __shared__ __align__(16) unsigned short halo[2][13824];   // 55296 B
  int t = threadIdx.x, wid = t >> 6, lane = t & 63;
  int g = lane >> 4, ln = lane & 15;
  int mg = wid & 1, ohalf = wid >> 1;
  int s0t = blockIdx.x * 2;
  int sA = s0t, sB = s0t + 1;
  int bA = sA / 343, rA = sA % 343;
  int zA = (rA/49)*4, yA = ((rA/7)%7)*4, xA = (rA%7)*4;
  int bB = sB / 343, rB = sB % 343;
  int zB = (rB/49)*4, yB = ((rB/7)%7)*4, xB = (rB%7)*4;
  int hp = (ln>>2)*6 + (ln&3);           // halo offset of row ln (m-tile adds mt*36)
  f32x4 acc[4][4] = {};                  // [nt][mt]
  // B-frag base: wbf idx (s,ks,nt) = s*8192 + ks*4096 + g*1024 + ohalf*512 + nt*128 + ln*8
  const unsigned short* wb0 = wbf + (size_t)(g*1024 + ohalf*512 + ln*8);
  bf16x8 b0[8], b1[8];

  #define BLOADX(dst_, s_) do { \
    const unsigned short* wp_ = wb0 + (size_t)(s_)*8192; \
    _Pragma("unroll") \
    for (int ks_ = 0; ks_ < 2; ++ks_) \
      _Pragma("unroll") \
      for (int nt_ = 0; nt_ < 4; ++nt_) \
        dst_[ks_*4+nt_] = *reinterpret_cast<const bf16x8*>(wp_ + ks_*4096 + nt_*128); \
  } while(0)

  #define COMPUTE(tap_, buf_) do { \
    int dz_ = (tap_)/9, r9_ = (tap_)%9, dy_ = r9_/3, dx_ = r9_%3; \
    int off_ = dz_*36 + dy_*6 + dx_; \
    bf16x8 af_[2][4]; \
    _Pragma("unroll") \
    for (int ks_ = 0; ks_ < 2; ++ks_) \
      _Pragma("unroll") \
      for (int mt_ = 0; mt_ < 4; ++mt_) \
        af_[ks_][mt_] = *reinterpret_cast<const bf16x8*>( \
            &halo[mg][((ks_*4 + g)*216 + mt_*36 + hp + off_)*8]); \
    _Pragma("unroll") \
    for (int nt_ = 0; nt_ < 4; ++nt_) \
      _Pragma("unroll") \
      for (int ks_ = 0; ks_ < 2; ++ks_) \
        _Pragma("unroll") \
        for (int mt_ = 0; mt_ < 4; ++mt_) \
          acc[nt_][mt_] = __builtin_amdgcn_mfma_f32_16x16x32_bf16( \
              af_[ks_][mt_], buf_[ks_*4+nt_], acc[nt_][mt_], 0, 0, 0); \
  } while(0)

  int s = 0;
  BLOADX(b0, 0);
  for (int h = 0; h < 2; ++h){
    if (h) __syncthreads();              // all waves done reading h=0 halo
    for (int cidx = t; cidx < 3456; cidx += 256){
      int tile = cidx / 1728, ci = cidx - tile*1728;
      int kgr = ci / 216, pos = ci % 216;
      int uz = pos / 36, r36 = pos % 36, uy = r36 / 6, ux = r36 % 6;
      int z0_ = tile ? zB : zA, y0_ = tile ? yB : yA, x0_ = tile ? xB : xA;
      int b_  = tile ? bB : bA;
      int zz = z0_ - 1 + uz, yy = y0_ - 1 + uy, xx = x0_ - 1 + ux;
      uint4 v = make_uint4(0u,0u,0u,0u);
      if (zz >= 0 && zz < 28 && yy >= 0 && yy < 28 && xx >= 0 && xx < 28)
        v = *reinterpret_cast<const uint4*>(
              &xag[(((size_t)b_*SP) + zz*784 + yy*28 + xx)*128 + h*64 + kgr*8]);
      *reinterpret_cast<uint4*>(&halo[tile][(size_t)ci*8]) = v;
    }
    __syncthreads();
    for (int tp = 0; tp < 26; tp += 2){
      BLOADX(b1, s+1);
      COMPUTE(tp, b0);
      BLOADX(b0, s+2);
      COMPUTE(tp+1, b1);
      s += 2;
    }
    COMPUTE(26, b0);                     // tap 26 of this h
    ++s;                                 // s = 27 (after h=0) or 54
    if (s < 54) BLOADX(b0, s);           // prefetch (h=1, tap=0) across barrier
  }
  {
    int zM = mg ? zB : zA, yM = mg ? yB : yA, xM = mg ? xB : xA;
    int bM = mg ? bB : bA;
    #pragma unroll
    for (int nt = 0; nt < 4; ++nt){
      int oc = ohalf*64 + nt*16 + ln;
      #pragma unroll
      for (int mt = 0; mt < 4; ++mt){
        #pragma unroll
        for (int r = 0; r < 4; ++r){
          int pos = (zM + mt)*784 + (yM + g)*28 + (xM + r);
          yg[((size_t)bM*SP + pos)*128 + oc] = f2b(acc[nt][mt][r]);
        }
      }
    }
  }
  #undef BLOADX
  #undef COMPUTE
}

// K5 v2: per-channel sum/sumsq of y, uint4 loads (8 ch per thread), shfl +
// LDS-atomic reduction.
__global__ __launch_bounds__(256) void k5_ystats(const unsigned short* __restrict__ yg,
                                                 float* __restrict__ misc){
  int t = threadIdx.x;
  int c8 = t & 15;          // channel group: channels c8*8 .. c8*8+7
  int pr = t >> 4;          // position row 0..15
  float s[8] = {0,0,0,0,0,0,0,0}, q[8] = {0,0,0,0,0,0,0,0};
  size_t base = (size_t)blockIdx.x * 256;   // 256 positions per block, grid 343
  for (int i = 0; i < 16; ++i){
    size_t pos = base + i*16 + pr;
    uint4 v = *reinterpret_cast<const uint4*>(yg + pos*128 + c8*8);
    #pragma unroll
    for (int j = 0; j < 4; ++j){
      unsigned int u = (&v.x)[j];
      float f0 = __uint_as_float(u << 16);
      float f1 = __uint_as_float(u & 0xffff0000u);
      s[2*j]   += f0; q[2*j]   += f0*f0;
      s[2*j+1] += f1; q[2*j+1] += f1*f1;
    }
  }
  #pragma unroll
  for (int j = 0; j < 8; ++j){
    s[j] += __shfl_xor(s[j], 16); q[j] += __shfl_xor(q[j], 16);
    s[j] += __shfl_xor(s[j], 32); q[j] += __shfl_xor(q[j], 32);
  }
  __shared__ float rs[128], rq[128];
  if (t < 128){ rs[t] = 0.f; rq[t] = 0.f; }
  __syncthreads();
  if ((t & 48) == 0){   // lanes 0..15 of each wave hold the wave partials
    #pragma unroll
    for (int j = 0; j < 8; ++j){
      atomicAdd(&rs[c8*8+j], s[j]);
      atomicAdd(&rq[c8*8+j], q[j]);
    }
  }
  __syncthreads();
  if (t < 128){
    atomicAdd(&misc[MISC_SUM + t], rs[t]);
    atomicAdd(&misc[MISC_SQ  + t], rq[t]);
  }
}

__global__ void k5b_finstats(const float* __restrict__ gcl, const float* __restrict__ bcl,
                             float* __restrict__ misc){
  int c = threadIdx.x;
  float mean = misc[MISC_SUM+c] / (float)PT;
  float var  = misc[MISC_SQ +c] / (float)PT - mean*mean;
  float a = gcl[c] * rsqrtf(var + EPS_);
  misc[MISC_A2+c] = a;
  misc[MISC_B2+c] = bcl[c] - mean*a;
}

// K6 (MFMA): out = shortcut + Wproj @ (x_att + silu(bn(y))) with split-bf16
// fp32 emulation (wh*bh + wl*bh + wh*bl).
__global__ __launch_bounds__(256) void k6_final(const unsigned short* __restrict__ xag,
        const unsigned short* __restrict__ yg, const unsigned short* __restrict__ w6,
        const float* __restrict__ xin, const float* __restrict__ misc,
        float* __restrict__ out){
  __shared__ __align__(16) unsigned short xh[8192];   // 16KB
  __shared__ __align__(16) unsigned short xl[8192];   // 16KB
  __shared__ float a2s[128], b2s[128];
  int t = threadIdx.x;
  int P0 = blockIdx.x * 64;
  int b = P0 / SP, sp0 = P0 % SP;
  if (t < 128){ a2s[t] = misc[MISC_A2+t]; b2s[t] = misc[MISC_B2+t]; }
  __syncthreads();
  // stage: v = xatt + silu(bn(y)) -> bf16 hi/lo, swizzled [pos][c]
  for (int idx = t; idx < 1024; idx += 256){
    int p = idx >> 4, c0 = (idx & 15) * 8;
    size_t gb = (size_t)(P0 + p)*128 + c0;
    uint4 yv4 = *reinterpret_cast<const uint4*>(yg + gb);
    uint4 xa4 = *reinterpret_cast<const uint4*>(xag + gb);
    unsigned int ph[4], pl[4];
    #pragma unroll
    for (int j = 0; j < 4; ++j){
      unsigned int uy = (&yv4.x)[j], ux = (&xa4.x)[j];
      int c = c0 + 2*j;
      float y0 = __uint_as_float(uy << 16)          * a2s[c]   + b2s[c];
      float y1 = __uint_as_float(uy & 0xffff0000u)  * a2s[c+1] + b2s[c+1];
      float v0 = __uint_as_float(ux << 16)         + y0 / (1.f + __expf(-y0));
      float v1 = __uint_as_float(ux & 0xffff0000u) + y1 / (1.f + __expf(-y1));
      unsigned short h0 = f2b(v0), h1 = f2b(v1);
      unsigned short l0 = f2b(v0 - b2f(h0)), l1 = f2b(v1 - b2f(h1));
      ph[j] = (unsigned int)h0 | ((unsigned int)h1 << 16);
      pl[j] = (unsigned int)l0 | ((unsigned int)l1 << 16);
    }
    int byte = (p*256 + c0*2) ^ ((p & 7) << 4);
    *reinterpret_cast<uint4*>((char*)xh + byte) = make_uint4(ph[0],ph[1],ph[2],ph[3]);
    *reinterpret_cast<uint4*>((char*)xl + byte) = make_uint4(pl[0],pl[1],pl[2],pl[3]);
  }
  __syncthreads();
  int wid = t >> 6, lane = t & 63;
  int g = lane >> 4, ln = lane & 15;
  f32x4 acc[2][4] = {};    // [o-tile][pos-tile]
  #pragma unroll 1
  for (int kk = 0; kk < 4; ++kk){
    bf16x8 bh[4], bl[4];
    #pragma unroll
    for (int pt = 0; pt < 4; ++pt){
      int row = pt*16 + ln;
      int byte = (row*256 + kk*64 + g*16) ^ ((ln & 7) << 4);
      bh[pt] = *reinterpret_cast<const bf16x8*>((const char*)xh + byte);
      bl[pt] = *reinterpret_cast<const bf16x8*>((const char*)xl + byte);
    }
    #pragma unroll
    for (int ot = 0; ot < 2; ++ot){
      int o = wid*32 + ot*16 + ln;
      const unsigned short* wp = w6 + (size_t)o*128 + kk*32 + g*8;
      bf16x8 wh = *reinterpret_cast<const bf16x8*>(wp);
      bf16x8 wl = *reinterpret_cast<const bf16x8*>(wp + 16384);
      #pragma unroll
      for (int pt = 0; pt < 4; ++pt){
        acc[ot][pt] = __builtin_amdgcn_mfma_f32_16x16x32_bf16(wh, bh[pt], acc[ot][pt], 0, 0, 0);
        acc[ot][pt] = __builtin_amdgcn_mfma_f32_16x16x32_bf16(wl, bh[pt], acc[ot][pt], 0, 0, 0);
        acc[ot][pt] = __builtin_amdgcn_mfma_f32_16x16x32_bf16(wh, bl[pt], acc[ot][pt], 0, 0, 0);
      }
    }
  }
  #pragma unroll
  for (int ot = 0; ot < 2; ++ot){
    #pragma unroll
    for (int r = 0; r < 4; ++r){
      int o = wid*32 + ot*16 + g*4 + r;
      size_t gbase = ((size_t)b*128 + o)*SP + sp0;
      #pragma unroll
      for (int pt = 0; pt < 4; ++pt){
        size_t gaddr = gbase + pt*16 + ln;
        out[gaddr] = xin[gaddr] + acc[ot][pt][r];
      }
    }
  }
}

extern "C" void kernel_launch(void* const* d_in, const int* in_sizes, int n_in,
                              void* d_out, int out_size, void* d_ws, size_t ws_size,
                              hipStream_t stream){
  const float* x      = (const float*)d_in[0];
  const float* g_in   = (const float*)d_in[1];
  const float* b_in   = (const float*)d_in[2];
  const float* w_qk   = (const float*)d_in[3];
  const float* w_v    = (const float*)d_in[4];
  const float* w_cl   = (const float*)d_in[5];
  const float* g_cl   = (const float*)d_in[6];
  const float* b_cl   = (const float*)d_in[7];
  const float* w_proj = (const float*)d_in[8];
  float* out = (float*)d_out;

  char* ws = (char*)d_ws;
  unsigned short* qg  = (unsigned short*)ws;
  unsigned short* kgp = qg  + 11239424;
  unsigned short* vg  = kgp + 11239424;
  unsigned short* xag = vg  + 11239424;
  unsigned short* yg  = xag + 11239424;
  float* misc = (float*)(ws + (size_t)5*22478848);   // 112,394,240 B offset
  unsigned short* wbf = qg;            // reuses qg region AFTER k3 consumed q
  unsigned short* w6  = qg + 524288;   // proj hi/lo weights, past wbf's 442368
  unsigned short* w2  = yg;            // qkv hi/lo weights; yg free until k4

  hipMemsetAsync(misc + MISC_SUM, 0, 768*sizeof(float), stream);
  k0_partial  <<<1024, 256, 0, stream>>>(x, misc);
  k1_bias     <<<3, 128, 0, stream>>>(w_qk, w_v, g_in, b_in, misc);
  k1w         <<<192, 256, 0, stream>>>(w_qk, w_v, w2);
  k2_qkv      <<<1372, 256, 0, stream>>>(x, w2, misc, qg, kgp, vg);
  k3_attn     <<<1024, 256, 0, stream>>>(qg, kgp, vg, xag);
  k_wprep     <<<1728, 256, 0, stream>>>(w_cl, wbf);
  k6w         <<<64, 256, 0, stream>>>(w_proj, w6);
  k4_mfma     <<<686, 256, 0, stream>>>(xag, wbf, yg);
  k5_ystats   <<<343, 256, 0, stream>>>(yg, misc);
  k5b_finstats<<<1, 128, 0, stream>>>(g_cl, b_cl, misc);
  k6_final    <<<1372, 256, 0, stream>>>(xag, yg, w6, x, misc, out);
}

// Round 6
// 360.964 us; speedup vs baseline: 1.1025x; 1.1025x over previous
//
#include <hip/hip_runtime.h>
#include <hip/hip_bf16.h>

// Problem constants
#define C      128
#define SP     21952          // 28*28*28
#define PT     87808          // 4*SP
#define LW     343            // 7^3 window length
#define EPS_   1e-6f
#define SCALE_ 0.17677669529663687f  // 32^-0.5

// misc workspace layout (floats)
#define MISC_A   0
#define MISC_B   128
#define MISC_BQK 256
#define MISC_BV  512
#define MISC_SUM 640
#define MISC_SQ  768
#define MISC_A2  896
#define MISC_B2  1024
#define MISC_XS  1152
#define MISC_XQ  1280

typedef __attribute__((ext_vector_type(8))) short bf16x8;
typedef __attribute__((ext_vector_type(4))) float f32x4;

__device__ __forceinline__ float b2f(unsigned short u){
  return __uint_as_float(((unsigned int)u) << 16);
}
__device__ __forceinline__ unsigned short f2b(float f){
  unsigned int u = __float_as_uint(f);
  u += 0x7fffu + ((u >> 16) & 1u);     // round-to-nearest-even
  return (unsigned short)(u >> 16);
}

// K0: per-channel partial sum/sumsq of x, 1024 blocks, float4 loads.
__global__ __launch_bounds__(256) void k0_partial(const float* __restrict__ x,
                                                  float* __restrict__ misc){
  int c = blockIdx.x & 127, chunk = blockIdx.x >> 7;   // 8 chunks = 4 batch x 2 halves
  int bb = chunk >> 1, half = chunk & 1;
  const float4* p = reinterpret_cast<const float4*>(
      x + (size_t)(bb*C + c)*SP + half*10976);
  int t = threadIdx.x;
  float s = 0.f, ss = 0.f;
  for (int i = t; i < 2744; i += 256){
    float4 v = p[i];
    s  += v.x + v.y + v.z + v.w;
    ss += v.x*v.x + v.y*v.y + v.z*v.z + v.w*v.w;
  }
  #pragma unroll
  for (int off = 32; off > 0; off >>= 1){
    s  += __shfl_xor(s,  off);
    ss += __shfl_xor(ss, off);
  }
  __shared__ float red[8];
  int wid = t >> 6, lane = t & 63;
  if (lane == 0){ red[wid] = s; red[4+wid] = ss; }
  __syncthreads();
  if (t == 0){
    atomicAdd(&misc[MISC_XS + c], red[0]+red[1]+red[2]+red[3]);
    atomicAdd(&misc[MISC_XQ + c], red[4]+red[5]+red[6]+red[7]);
  }
}

// K1: finalize BN stats (from k0 partials) + fold shift through 1x1 weights.
__global__ void k1_bias(const float* __restrict__ wqk, const float* __restrict__ wvv,
                        const float* __restrict__ gin, const float* __restrict__ bin,
                        float* __restrict__ misc){
  __shared__ float bv[128];
  int t = threadIdx.x;          // 128 threads, grid 3
  {
    float mean = misc[MISC_XS + t] / (float)PT;
    float var  = misc[MISC_XQ + t] / (float)PT - mean*mean;
    float a = rsqrtf(var + EPS_) * gin[t];
    float bb = bin[t] - mean * a;
    bv[t] = bb;
    if (blockIdx.x == 0){ misc[MISC_A + t] = a; misc[MISC_B + t] = bb; }
  }
  __syncthreads();
  int o = blockIdx.x*128 + t;
  float acc = 0.f;
  if (o < 256){
    const float* wr = wqk + (size_t)o*128;
    for (int c = 0; c < 128; ++c) acc += wr[c]*bv[c];
    misc[MISC_BQK + o] = acc;
  } else {
    const float* wr = wvv + (size_t)(o-256)*128;
    for (int c = 0; c < 128; ++c) acc += wr[c]*bv[c];
    misc[MISC_BV + (o-256)] = acc;
  }
}

// K1w: split qkv weights into bf16 hi/lo pairs: w2[0..49152) = hi, [49152..) = lo
__global__ void k1w(const float* __restrict__ wqk, const float* __restrict__ wvv,
                    unsigned short* __restrict__ w2){
  int idx = blockIdx.x*256 + threadIdx.x;   // 49152 total
  int o = idx >> 7;
  float w = (o < 256) ? wqk[idx] : wvv[idx - 32768];
  unsigned short h = f2b(w);
  w2[idx] = h;
  w2[49152 + idx] = f2b(w - b2f(h));
}

// K2 (MFMA): qkv projection on mfma_f32_16x16x32_bf16 with split-bf16
// fp32 emulation: out = xh*wh + xl*wh + xh*wl (missing xl*wl ~ 2^-18 relative).
__global__ __launch_bounds__(256) void k2_qkv(const float* __restrict__ x,
        const unsigned short* __restrict__ w2, const float* __restrict__ misc,
        unsigned short* __restrict__ qg, unsigned short* __restrict__ kg,
        unsigned short* __restrict__ vg){
  __shared__ __align__(16) unsigned short xh[8192];   // 16KB
  __shared__ __align__(16) unsigned short xl[8192];   // 16KB
  __shared__ float ascale[128];
  __shared__ unsigned int posTab[64];
  int t = threadIdx.x;
  int P0 = blockIdx.x * 64;
  int b = P0 / SP, sp0 = P0 % SP;
  if (t < 128) ascale[t] = misc[MISC_A + t];
  if (t < 64){
    int sp = sp0 + t;
    int h_ = sp / 784, rem = sp % 784;
    int w_ = rem / 28, d_ = rem % 28;
    int w1 = h_ & 3, s1 = h_ >> 2;
    int w2i = w_ & 3, s2 = w_ >> 2;
    int w3 = d_ & 3, s3 = d_ >> 2;
    int bw = ((b*4 + w1)*4 + w2i)*4 + w3;
    int l  = (s1*7 + s2)*7 + s3;
    posTab[t] = (unsigned int)(bw*43904 + l*32);   // ushort offset, +h*10976+d at store
  }
  __syncthreads();
  // stage x -> bf16 hi/lo (BN scale folded), swizzled
  {
    int p = t & 63;
    int ob = t >> 6;
    const float* xb = x + (size_t)b*C*SP + sp0 + p;
    for (int it = 0; it < 4; ++it){
      int c0 = (ob + it*4) * 8;
      unsigned int ph[4], pl[4];
      #pragma unroll
      for (int j = 0; j < 4; ++j){
        float f0 = xb[(size_t)(c0 + 2*j)*SP]     * ascale[c0 + 2*j];
        float f1 = xb[(size_t)(c0 + 2*j + 1)*SP] * ascale[c0 + 2*j + 1];
        unsigned short h0 = f2b(f0), h1 = f2b(f1);
        unsigned short l0 = f2b(f0 - b2f(h0)), l1 = f2b(f1 - b2f(h1));
        ph[j] = (unsigned int)h0 | ((unsigned int)h1 << 16);
        pl[j] = (unsigned int)l0 | ((unsigned int)l1 << 16);
      }
      int byte = (p*256 + c0*2) ^ ((p & 7) << 4);
      *reinterpret_cast<uint4*>((char*)xh + byte) = make_uint4(ph[0],ph[1],ph[2],ph[3]);
      *reinterpret_cast<uint4*>((char*)xl + byte) = make_uint4(pl[0],pl[1],pl[2],pl[3]);
    }
  }
  __syncthreads();
  int wid = t >> 6, lane = t & 63;
  int g = lane >> 4, ln = lane & 15;
  int wstart = wid * 96;
  f32x4 acc[6][4];
  #pragma unroll
  for (int nt = 0; nt < 6; ++nt){
    float bv = misc[256 + wstart + nt*16 + ln];
    #pragma unroll
    for (int mt = 0; mt < 4; ++mt) acc[nt][mt] = (f32x4){bv,bv,bv,bv};
  }
  #pragma unroll 1
  for (int kk = 0; kk < 4; ++kk){
    bf16x8 ah[4], al[4];
    #pragma unroll
    for (int mt = 0; mt < 4; ++mt){
      int row = mt*16 + ln;
      int byte = (row*256 + kk*64 + g*16) ^ ((ln & 7) << 4);
      ah[mt] = *reinterpret_cast<const bf16x8*>((const char*)xh + byte);
      al[mt] = *reinterpret_cast<const bf16x8*>((const char*)xl + byte);
    }
    #pragma unroll
    for (int nt = 0; nt < 6; ++nt){
      int o = wstart + nt*16 + ln;
      const unsigned short* wp = w2 + (size_t)o*128 + kk*32 + g*8;
      bf16x8 whf = *reinterpret_cast<const bf16x8*>(wp);
      bf16x8 wlf = *reinterpret_cast<const bf16x8*>(wp + 49152);
      #pragma unroll
      for (int mt = 0; mt < 4; ++mt){
        acc[nt][mt] = __builtin_amdgcn_mfma_f32_16x16x32_bf16(ah[mt], whf, acc[nt][mt], 0, 0, 0);
        acc[nt][mt] = __builtin_amdgcn_mfma_f32_16x16x32_bf16(al[mt], whf, acc[nt][mt], 0, 0, 0);
        acc[nt][mt] = __builtin_amdgcn_mfma_f32_16x16x32_bf16(ah[mt], wlf, acc[nt][mt], 0, 0, 0);
      }
    }
  }
  // epilogue: relu on v, bf16, scatter (16 consecutive lanes = 32B contiguous)
  unsigned int ptab[16];
  #pragma unroll
  for (int mt = 0; mt < 4; ++mt)
    #pragma unroll
    for (int r = 0; r < 4; ++r)
      ptab[mt*4+r] = posTab[mt*16 + g*4 + r];
  #pragma unroll
  for (int nt = 0; nt < 6; ++nt){
    int o = wstart + nt*16 + ln;
    bool isv = (o >= 256);
    int oo = o & 127;
    unsigned short* dst = ((o < 128) ? qg : (o < 256 ? kg : vg)) + (oo >> 5)*10976 + (oo & 31);
    #pragma unroll
    for (int mt = 0; mt < 4; ++mt){
      #pragma unroll
      for (int r = 0; r < 4; ++r){
        float v = acc[nt][mt][r];
        if (isv) v = fmaxf(v, 0.f);
        dst[ptab[mt*4+r]] = f2b(v);
      }
    }
  }
}

// K3 (MFMA): attention per (window, head) on mfma_f32_16x16x32_bf16.
__global__ __launch_bounds__(256) void k3_attn(const unsigned short* __restrict__ qg,
        const unsigned short* __restrict__ kg, const unsigned short* __restrict__ vg,
        unsigned short* __restrict__ xatt){
  __shared__ __align__(16) unsigned short klds[352*32];    // [m][d]     22528 B
  __shared__ __align__(16) unsigned short vper[32*360];    // [d][m']    23040 B
  __shared__ __align__(16) unsigned short pbuf[4][640];    // per-wave [16][40]
  int bh = blockIdx.x;
  int bw = bh >> 2, h = bh & 3;
  int t = threadIdx.x;
  int wid = t >> 6, lane = t & 63;
  int g = lane >> 4, ln = lane & 15;
  const unsigned short* kbase = kg + (size_t)bh*LW*32;
  const unsigned short* vbase = vg + (size_t)bh*LW*32;
  const unsigned short* qbase = qg + (size_t)bh*LW*32;
  // stage K: straight uint4 copy, zero pad rows 343..351
  {
    const uint4* src = reinterpret_cast<const uint4*>(kbase);
    uint4* dst = reinterpret_cast<uint4*>(klds);
    for (int i = t; i < 1372; i += 256) dst[i] = src[i];
    for (int i = t; i < 288; i += 256) klds[10976 + i] = 0;
  }
  // stage V transposed + 32-key interleave: m -> (c = m>>5, pk = 2*(m&15) | ((m>>4)&1))
  for (int idx = t; idx < 10976; idx += 256){
    int m = idx >> 5, d = idx & 31;
    int km = m & 31;
    int pk = ((km & 15) << 1) | (km >> 4);
    vper[d*360 + ((m >> 5) << 5) + pk] = vbase[idx];
  }
  for (int i = t; i < 288; i += 256){       // zero V pad rows 343..351
    int m = 343 + (i >> 5), d = i & 31;
    int km = m & 31;
    int pk = ((km & 15) << 1) | (km >> 4);
    vper[d*360 + 320 + pk] = 0;
  }
  __syncthreads();
  int w1 = (bw>>4)&3, w2 = (bw>>2)&3, w3 = bw&3, b = bw>>6;
  unsigned short* pb = pbuf[wid];
  const f32x4 zero4 = {0.f, 0.f, 0.f, 0.f};
  for (int rt = wid; rt < 22; rt += 4){
    int row0 = rt << 4;
    bf16x8 qf = *reinterpret_cast<const bf16x8*>(qbase + (size_t)(row0 + ln)*32 + g*8);
    // QK^T: 22 n-tiles, single k-step (K=32=DH)
    f32x4 s[22];
    #pragma unroll
    for (int nt = 0; nt < 22; ++nt){
      bf16x8 kf = *reinterpret_cast<const bf16x8*>(&klds[(nt*16 + ln)*32 + g*8]);
      s[nt] = __builtin_amdgcn_mfma_f32_16x16x32_bf16(qf, kf, zero4, 0, 0, 0);
    }
    float mxs[4];
    #pragma unroll
    for (int q = 0; q < 4; ++q){
      float m0 = -1e30f;
      #pragma unroll
      for (int nt = 0; nt < 21; ++nt) m0 = fmaxf(m0, s[nt][q]);
      if (ln < 7) m0 = fmaxf(m0, s[21][q]);
      #pragma unroll
      for (int off = 8; off > 0; off >>= 1) m0 = fmaxf(m0, __shfl_xor(m0, off));
      mxs[q] = m0 * SCALE_;
    }
    f32x4 o0 = zero4, o1 = zero4;
    float sums[4] = {0.f, 0.f, 0.f, 0.f};
    #pragma unroll
    for (int c = 0; c < 11; ++c){
      #pragma unroll
      for (int q = 0; q < 4; ++q){
        float e0 = __expf(fmaf(s[2*c][q],   SCALE_, -mxs[q]));
        float e1 = (c*32 + 16 + ln < 343)
                 ? __expf(fmaf(s[2*c+1][q], SCALE_, -mxs[q])) : 0.f;
        sums[q] += e0 + e1;
        unsigned int pkd;
        asm volatile("v_cvt_pk_bf16_f32 %0, %1, %2" : "=v"(pkd) : "v"(e0), "v"(e1));
        *reinterpret_cast<unsigned int*>(&pb[(g*4+q)*40 + (ln<<1)]) = pkd;
      }
      asm volatile("s_waitcnt lgkmcnt(0)" ::: "memory");
      __builtin_amdgcn_sched_barrier(0);
      bf16x8 pa  = *reinterpret_cast<const bf16x8*>(&pb[ln*40 + g*8]);
      bf16x8 vb0 = *reinterpret_cast<const bf16x8*>(&vper[ln*360       + (c<<5) + g*8]);
      bf16x8 vb1 = *reinterpret_cast<const bf16x8*>(&vper[(16+ln)*360  + (c<<5) + g*8]);
      o0 = __builtin_amdgcn_mfma_f32_16x16x32_bf16(pa, vb0, o0, 0, 0, 0);
      o1 = __builtin_amdgcn_mfma_f32_16x16x32_bf16(pa, vb1, o1, 0, 0, 0);
    }
    float iss[4];
    #pragma unroll
    for (int q = 0; q < 4; ++q){
      float sq = sums[q];
      #pragma unroll
      for (int off = 8; off > 0; off >>= 1) sq += __shfl_xor(sq, off);
      iss[q] = 1.f / sq;
    }
    #pragma unroll
    for (int q = 0; q < 4; ++q){
      int l = row0 + g*4 + q;
      if (l < 343){
        int ss1 = l/49, ss2 = (l/7)%7, ss3 = l%7;
        int sp = (ss1*4+w1)*784 + (ss2*4+w2)*28 + (ss3*4+w3);
        size_t gaddr = ((size_t)b*SP + sp)*128 + h*32;
        xatt[gaddr + ln]      = f2b(o0[q]*iss[q]);
        xatt[gaddr + 16 + ln] = f2b(o1[q]*iss[q]);
      }
    }
  }
}

// K_wprep: w_cl [oc][ic][27] fp32 -> wbf bf16 slices [h][tap][kg][oc][8]
__global__ void k_wprep(const float* __restrict__ wcl, unsigned short* __restrict__ wbf){
  int f = blockIdx.x*256 + threadIdx.x;      // 442368 total
  int j  = f & 7;
  int oc = (f >> 3) & 127;
  int kgr= (f >> 10) & 7;
  int sl = f >> 13;                          // 0..53
  int h  = sl / 27, tap = sl % 27;
  int ic = h*64 + kgr*8 + j;
  wbf[f] = f2b(wcl[((size_t)oc*128 + ic)*27 + tap]);
}

// K6w: split proj weights into bf16 hi/lo pairs: w6[0..16384) hi, [16384..) lo
__global__ void k6w(const float* __restrict__ wproj, unsigned short* __restrict__ w6){
  int idx = blockIdx.x*256 + threadIdx.x;   // 16384 total
  float w = wproj[idx];
  unsigned short h = f2b(w);
  w6[idx] = h;
  w6[16384 + idx] = f2b(w - b2f(h));
}

// K4 v4: 3x3x3 conv as implicit GEMM on mfma_f32_16x16x32_bf16.
// v3 post-mortem: VGPR stayed 88 — __launch_bounds__(256,2) raised the ceiling
// but the pre-RA scheduler still sank each B-load to just before its MFMA
// (minimizing pressure), exposing ~500cy L2 latency per load. v4 pins the
// schedule with sched_group_barrier (T19): per tap {8 VMEM_READ (next-tap
// weights)} -> {8 DS_READ (A-frags)} -> {32 MFMA}. Loads become live across
// the MFMA cluster -> RA must keep b0/b1 in regs; latency hides under MFMA.
__global__ __launch_bounds__(256, 2) void k4_mfma(const unsigned short* __restrict__ xag,
        const unsigned short* __restrict__ wbf, unsigned short* __restrict__ yg){
  __shared__ __align__(16) unsigned short halo[2][13824];   // 55296 B
  int t = threadIdx.x, wid = t >> 6, lane = t & 63;
  int g = lane >> 4, ln = lane & 15;
  int mg = wid & 1, ohalf = wid >> 1;
  int s0t = blockIdx.x * 2;
  int sA = s0t, sB = s0t + 1;
  int bA = sA / 343, rA = sA % 343;
  int zA = (rA/49)*4, yA = ((rA/7)%7)*4, xA = (rA%7)*4;
  int bB = sB / 343, rB = sB % 343;
  int zB = (rB/49)*4, yB = ((rB/7)%7)*4, xB = (rB%7)*4;
  int hp = (ln>>2)*6 + (ln&3);           // halo offset of row ln (m-tile adds mt*36)
  f32x4 acc[4][4] = {};                  // [nt][mt]
  // B-frag base: wbf idx (s,ks,nt) = s*8192 + ks*4096 + g*1024 + ohalf*512 + nt*128 + ln*8
  const unsigned short* wb0 = wbf + (size_t)(g*1024 + ohalf*512 + ln*8);
  bf16x8 b0[8], b1[8];

  #define BLOADX(dst_, s_) do { \
    const unsigned short* wp_ = wb0 + (size_t)(s_)*8192; \
    _Pragma("unroll") \
    for (int ks_ = 0; ks_ < 2; ++ks_) \
      _Pragma("unroll") \
      for (int nt_ = 0; nt_ < 4; ++nt_) \
        dst_[ks_*4+nt_] = *reinterpret_cast<const bf16x8*>(wp_ + ks_*4096 + nt_*128); \
  } while(0)

  #define COMPUTE(tap_, buf_) do { \
    int dz_ = (tap_)/9, r9_ = (tap_)%9, dy_ = r9_/3, dx_ = r9_%3; \
    int off_ = dz_*36 + dy_*6 + dx_; \
    bf16x8 af_[2][4]; \
    _Pragma("unroll") \
    for (int ks_ = 0; ks_ < 2; ++ks_) \
      _Pragma("unroll") \
      for (int mt_ = 0; mt_ < 4; ++mt_) \
        af_[ks_][mt_] = *reinterpret_cast<const bf16x8*>( \
            &halo[mg][((ks_*4 + g)*216 + mt_*36 + hp + off_)*8]); \
    _Pragma("unroll") \
    for (int nt_ = 0; nt_ < 4; ++nt_) \
      _Pragma("unroll") \
      for (int ks_ = 0; ks_ < 2; ++ks_) \
        _Pragma("unroll") \
        for (int mt_ = 0; mt_ < 4; ++mt_) \
          acc[nt_][mt_] = __builtin_amdgcn_mfma_f32_16x16x32_bf16( \
              af_[ks_][mt_], buf_[ks_*4+nt_], acc[nt_][mt_], 0, 0, 0); \
  } while(0)

  // T19 pin: 8 weight loads batched first, then 8 A ds_reads, then 32 MFMAs.
  #define SGB_TAP() do { \
    __builtin_amdgcn_sched_group_barrier(0x020, 8, 0);   /* VMEM_READ */ \
    __builtin_amdgcn_sched_group_barrier(0x100, 8, 0);   /* DS_READ   */ \
    __builtin_amdgcn_sched_group_barrier(0x008, 32, 0);  /* MFMA      */ \
  } while(0)

  int s = 0;
  BLOADX(b0, 0);
  for (int h = 0; h < 2; ++h){
    if (h) __syncthreads();              // all waves done reading h=0 halo
    for (int cidx = t; cidx < 3456; cidx += 256){
      int tile = cidx / 1728, ci = cidx - tile*1728;
      int kgr = ci / 216, pos = ci % 216;
      int uz = pos / 36, r36 = pos % 36, uy = r36 / 6, ux = r36 % 6;
      int z0_ = tile ? zB : zA, y0_ = tile ? yB : yA, x0_ = tile ? xB : xA;
      int b_  = tile ? bB : bA;
      int zz = z0_ - 1 + uz, yy = y0_ - 1 + uy, xx = x0_ - 1 + ux;
      uint4 v = make_uint4(0u,0u,0u,0u);
      if (zz >= 0 && zz < 28 && yy >= 0 && yy < 28 && xx >= 0 && xx < 28)
        v = *reinterpret_cast<const uint4*>(
              &xag[(((size_t)b_*SP) + zz*784 + yy*28 + xx)*128 + h*64 + kgr*8]);
      *reinterpret_cast<uint4*>(&halo[tile][(size_t)ci*8]) = v;
    }
    __syncthreads();
    for (int tp = 0; tp < 26; tp += 2){
      BLOADX(b1, s+1);
      COMPUTE(tp, b0);
      SGB_TAP();
      BLOADX(b0, s+2);
      COMPUTE(tp+1, b1);
      SGB_TAP();
      s += 2;
    }
    {
      // tap 26 of this h; prefetch (h=1, tap 0) across the staging barrier
      if (s + 1 < 54) BLOADX(b1, s+1);
      COMPUTE(26, b0);
      SGB_TAP();
      ++s;                               // s = 27 (after h=0) or 54
      #pragma unroll
      for (int j = 0; j < 8; ++j) b0[j] = b1[j];
    }
  }
  {
    int zM = mg ? zB : zA, yM = mg ? yB : yA, xM = mg ? xB : xA;
    int bM = mg ? bB : bA;
    #pragma unroll
    for (int nt = 0; nt < 4; ++nt){
      int oc = ohalf*64 + nt*16 + ln;
      #pragma unroll
      for (int mt = 0; mt < 4; ++mt){
        #pragma unroll
        for (int r = 0; r < 4; ++r){
          int pos = (zM + mt)*784 + (yM + g)*28 + (xM + r);
          yg[((size_t)bM*SP + pos)*128 + oc] = f2b(acc[nt][mt][r]);
        }
      }
    }
  }
  #undef BLOADX
  #undef COMPUTE
  #undef SGB_TAP
}

// K5 v2: per-channel sum/sumsq of y, uint4 loads (8 ch per thread), shfl +
// LDS-atomic reduction.
__global__ __launch_bounds__(256) void k5_ystats(const unsigned short* __restrict__ yg,
                                                 float* __restrict__ misc){
  int t = threadIdx.x;
  int c8 = t & 15;          // channel group: channels c8*8 .. c8*8+7
  int pr = t >> 4;          // position row 0..15
  float s[8] = {0,0,0,0,0,0,0,0}, q[8] = {0,0,0,0,0,0,0,0};
  size_t base = (size_t)blockIdx.x * 256;   // 256 positions per block, grid 343
  for (int i = 0; i < 16; ++i){
    size_t pos = base + i*16 + pr;
    uint4 v = *reinterpret_cast<const uint4*>(yg + pos*128 + c8*8);
    #pragma unroll
    for (int j = 0; j < 4; ++j){
      unsigned int u = (&v.x)[j];
      float f0 = __uint_as_float(u << 16);
      float f1 = __uint_as_float(u & 0xffff0000u);
      s[2*j]   += f0; q[2*j]   += f0*f0;
      s[2*j+1] += f1; q[2*j+1] += f1*f1;
    }
  }
  #pragma unroll
  for (int j = 0; j < 8; ++j){
    s[j] += __shfl_xor(s[j], 16); q[j] += __shfl_xor(q[j], 16);
    s[j] += __shfl_xor(s[j], 32); q[j] += __shfl_xor(q[j], 32);
  }
  __shared__ float rs[128], rq[128];
  if (t < 128){ rs[t] = 0.f; rq[t] = 0.f; }
  __syncthreads();
  if ((t & 48) == 0){   // lanes 0..15 of each wave hold the wave partials
    #pragma unroll
    for (int j = 0; j < 8; ++j){
      atomicAdd(&rs[c8*8+j], s[j]);
      atomicAdd(&rq[c8*8+j], q[j]);
    }
  }
  __syncthreads();
  if (t < 128){
    atomicAdd(&misc[MISC_SUM + t], rs[t]);
    atomicAdd(&misc[MISC_SQ  + t], rq[t]);
  }
}

__global__ void k5b_finstats(const float* __restrict__ gcl, const float* __restrict__ bcl,
                             float* __restrict__ misc){
  int c = threadIdx.x;
  float mean = misc[MISC_SUM+c] / (float)PT;
  float var  = misc[MISC_SQ +c] / (float)PT - mean*mean;
  float a = gcl[c] * rsqrtf(var + EPS_);
  misc[MISC_A2+c] = a;
  misc[MISC_B2+c] = bcl[c] - mean*a;
}

// K6 (MFMA): out = shortcut + Wproj @ (x_att + silu(bn(y))) with split-bf16
// fp32 emulation (wh*bh + wl*bh + wh*bl).
__global__ __launch_bounds__(256) void k6_final(const unsigned short* __restrict__ xag,
        const unsigned short* __restrict__ yg, const unsigned short* __restrict__ w6,
        const float* __restrict__ xin, const float* __restrict__ misc,
        float* __restrict__ out){
  __shared__ __align__(16) unsigned short xh[8192];   // 16KB
  __shared__ __align__(16) unsigned short xl[8192];   // 16KB
  __shared__ float a2s[128], b2s[128];
  int t = threadIdx.x;
  int P0 = blockIdx.x * 64;
  int b = P0 / SP, sp0 = P0 % SP;
  if (t < 128){ a2s[t] = misc[MISC_A2+t]; b2s[t] = misc[MISC_B2+t]; }
  __syncthreads();
  // stage: v = xatt + silu(bn(y)) -> bf16 hi/lo, swizzled [pos][c]
  for (int idx = t; idx < 1024; idx += 256){
    int p = idx >> 4, c0 = (idx & 15) * 8;
    size_t gb = (size_t)(P0 + p)*128 + c0;
    uint4 yv4 = *reinterpret_cast<const uint4*>(yg + gb);
    uint4 xa4 = *reinterpret_cast<const uint4*>(xag + gb);
    unsigned int ph[4], pl[4];
    #pragma unroll
    for (int j = 0; j < 4; ++j){
      unsigned int uy = (&yv4.x)[j], ux = (&xa4.x)[j];
      int c = c0 + 2*j;
      float y0 = __uint_as_float(uy << 16)          * a2s[c]   + b2s[c];
      float y1 = __uint_as_float(uy & 0xffff0000u)  * a2s[c+1] + b2s[c+1];
      float v0 = __uint_as_float(ux << 16)         + y0 / (1.f + __expf(-y0));
      float v1 = __uint_as_float(ux & 0xffff0000u) + y1 / (1.f + __expf(-y1));
      unsigned short h0 = f2b(v0), h1 = f2b(v1);
      unsigned short l0 = f2b(v0 - b2f(h0)), l1 = f2b(v1 - b2f(h1));
      ph[j] = (unsigned int)h0 | ((unsigned int)h1 << 16);
      pl[j] = (unsigned int)l0 | ((unsigned int)l1 << 16);
    }
    int byte = (p*256 + c0*2) ^ ((p & 7) << 4);
    *reinterpret_cast<uint4*>((char*)xh + byte) = make_uint4(ph[0],ph[1],ph[2],ph[3]);
    *reinterpret_cast<uint4*>((char*)xl + byte) = make_uint4(pl[0],pl[1],pl[2],pl[3]);
  }
  __syncthreads();
  int wid = t >> 6, lane = t & 63;
  int g = lane >> 4, ln = lane & 15;
  f32x4 acc[2][4] = {};    // [o-tile][pos-tile]
  #pragma unroll 1
  for (int kk = 0; kk < 4; ++kk){
    bf16x8 bh[4], bl[4];
    #pragma unroll
    for (int pt = 0; pt < 4; ++pt){
      int row = pt*16 + ln;
      int byte = (row*256 + kk*64 + g*16) ^ ((ln & 7) << 4);
      bh[pt] = *reinterpret_cast<const bf16x8*>((const char*)xh + byte);
      bl[pt] = *reinterpret_cast<const bf16x8*>((const char*)xl + byte);
    }
    #pragma unroll
    for (int ot = 0; ot < 2; ++ot){
      int o = wid*32 + ot*16 + ln;
      const unsigned short* wp = w6 + (size_t)o*128 + kk*32 + g*8;
      bf16x8 wh = *reinterpret_cast<const bf16x8*>(wp);
      bf16x8 wl = *reinterpret_cast<const bf16x8*>(wp + 16384);
      #pragma unroll
      for (int pt = 0; pt < 4; ++pt){
        acc[ot][pt] = __builtin_amdgcn_mfma_f32_16x16x32_bf16(wh, bh[pt], acc[ot][pt], 0, 0, 0);
        acc[ot][pt] = __builtin_amdgcn_mfma_f32_16x16x32_bf16(wl, bh[pt], acc[ot][pt], 0, 0, 0);
        acc[ot][pt] = __builtin_amdgcn_mfma_f32_16x16x32_bf16(wh, bl[pt], acc[ot][pt], 0, 0, 0);
      }
    }
  }
  #pragma unroll
  for (int ot = 0; ot < 2; ++ot){
    #pragma unroll
    for (int r = 0; r < 4; ++r){
      int o = wid*32 + ot*16 + g*4 + r;
      size_t gbase = ((size_t)b*128 + o)*SP + sp0;
      #pragma unroll
      for (int pt = 0; pt < 4; ++pt){
        size_t gaddr = gbase + pt*16 + ln;
        out[gaddr] = xin[gaddr] + acc[ot][pt][r];
      }
    }
  }
}

extern "C" void kernel_launch(void* const* d_in, const int* in_sizes, int n_in,
                              void* d_out, int out_size, void* d_ws, size_t ws_size,
                              hipStream_t stream){
  const float* x      = (const float*)d_in[0];
  const float* g_in   = (const float*)d_in[1];
  const float* b_in   = (const float*)d_in[2];
  const float* w_qk   = (const float*)d_in[3];
  const float* w_v    = (const float*)d_in[4];
  const float* w_cl   = (const float*)d_in[5];
  const float* g_cl   = (const float*)d_in[6];
  const float* b_cl   = (const float*)d_in[7];
  const float* w_proj = (const float*)d_in[8];
  float* out = (float*)d_out;

  char* ws = (char*)d_ws;
  unsigned short* qg  = (unsigned short*)ws;
  unsigned short* kgp = qg  + 11239424;
  unsigned short* vg  = kgp + 11239424;
  unsigned short* xag = vg  + 11239424;
  unsigned short* yg  = xag + 11239424;
  float* misc = (float*)(ws + (size_t)5*22478848);   // 112,394,240 B offset
  unsigned short* wbf = qg;            // reuses qg region AFTER k3 consumed q
  unsigned short* w6  = qg + 524288;   // proj hi/lo weights, past wbf's 442368
  unsigned short* w2  = yg;            // qkv hi/lo weights; yg free until k4

  hipMemsetAsync(misc + MISC_SUM, 0, 768*sizeof(float), stream);
  k0_partial  <<<1024, 256, 0, stream>>>(x, misc);
  k1_bias     <<<3, 128, 0, stream>>>(w_qk, w_v, g_in, b_in, misc);
  k1w         <<<192, 256, 0, stream>>>(w_qk, w_v, w2);
  k2_qkv      <<<1372, 256, 0, stream>>>(x, w2, misc, qg, kgp, vg);
  k3_attn     <<<1024, 256, 0, stream>>>(qg, kgp, vg, xag);
  k_wprep     <<<1728, 256, 0, stream>>>(w_cl, wbf);
  k6w         <<<64, 256, 0, stream>>>(w_proj, w6);
  k4_mfma     <<<686, 256, 0, stream>>>(xag, wbf, yg);
  k5_ystats   <<<343, 256, 0, stream>>>(yg, misc);
  k5b_finstats<<<1, 128, 0, stream>>>(g_cl, b_cl, misc);
  k6_final    <<<1372, 256, 0, stream>>>(xag, yg, w6, x, misc, out);
}